// Round 9
// baseline (1037.438 us; speedup 1.0000x reference)
//
#include <hip/hip_runtime.h>

// Transformer block + switch-MoE, MI355X gfx950. ALL I/O FLOAT32.
// R13: "other"-bucket + flash barrier cuts (GEMMs byte-identical to R10/R12).
//  - ffn1/ffn2: 8 slots per block (same expert) -> W1/W2 L2 traffic /8
//    (was ~1 GB each). Per-output FMA order unchanged -> numerics identical.
//  - flash: double-buffered Ks/Vs (64 KB LDS, still 2 blocks/CU), ONE
//    __syncthreads per k-tile (was 2). Prefetch issued AFTER the barrier so
//    its latency hides under compute (R8 lesson). Safety: readers@kt-2
//    precede BAR@kt-1 precede writers@kt. Ps remains wave-private.
//  - fill_mask folded into assemble.
// History: R12 flash 258->194us (__expf + MFMA row-sum, MfmaUtil 51%);
// R10 fixed-ref softmax; R6 gemm LDS-staging (~145us each, m97-class
// ceiling; R8/R9 pipelining nulls).

typedef __bf16 bf16;
typedef __bf16 bf16x4 __attribute__((ext_vector_type(4)));
typedef __bf16 bf16x8 __attribute__((ext_vector_type(8)));
typedef float  f32x4  __attribute__((ext_vector_type(4)));

#define NB    8
#define LL    1024
#define CC    1024
#define NH    16
#define DKD   64
#define NE    16
#define NHID  64
#define CAP   256
#define NTOK  (NB*LL)          // 8192
#define MB    (1024*1024)

__device__ __forceinline__ void gload16(const bf16* g, bf16* l)
{
    __builtin_amdgcn_global_load_lds(
        (const __attribute__((address_space(1))) void*)g,
        (__attribute__((address_space(3))) void*)l, 16, 0, 0);
}

__device__ inline void split3v(const f32x4 v, bf16x4& a, bf16x4& b, bf16x4& c)
{
#pragma unroll
    for (int k = 0; k < 4; k++) {
        const float x  = v[k];
        const bf16  hi = (bf16)x;
        const float r1 = x - (float)hi;
        const bf16  md = (bf16)r1;
        const float r2 = r1 - (float)md;
        a[k] = hi; b[k] = md; c[k] = (bf16)r2;
    }
}

__device__ inline bf16x8 pack8(const bf16x4 a, const bf16x4 b)
{
    bf16x8 r;
#pragma unroll
    for (int e = 0; e < 4; e++) { r[e] = a[e]; r[4 + e] = b[e]; }
    return r;
}

// ---------------- split f32 -> 3 bf16 limbs (hi, mid, lo) --------------------
__global__ __launch_bounds__(256)
void split3(const float* __restrict__ z, bf16* __restrict__ z1,
            bf16* __restrict__ z2, bf16* __restrict__ z3)
{
    const size_t i = ((size_t)blockIdx.x * 256 + threadIdx.x) * 4;
    const f32x4 v = *(const f32x4*)(z + i);
    bf16x4 a, b, c;
    split3v(v, a, b, c);
    *(bf16x4*)(z1 + i) = a;
    *(bf16x4*)(z2 + i) = b;
    *(bf16x4*)(z3 + i) = c;
}

// ------- GEMM: C[M,N] = A[M,K] @ W[N,K]^T + bias, A/W as 3 bf16 limbs -------
// R6 structure (verified, best measured): LDS-staged, 128x128 tile, BK=32,
// 4 waves (64x64 each), global_load_lds width=16.
__global__ __launch_bounds__(256)
void gemm_limb6(const bf16* __restrict__ A0, const bf16* __restrict__ A1,
                const bf16* __restrict__ A2,
                const bf16* __restrict__ W0, const bf16* __restrict__ W1l,
                const bf16* __restrict__ W2l,
                const float* __restrict__ bias, float* __restrict__ C,
                int M, int N, int K)
{
    __shared__ __align__(16) bf16 As[3][128][32];
    __shared__ __align__(16) bf16 Ws[3][128][32];

    const int tid  = threadIdx.x;
    const int lane = tid & 63;
    const int wv   = tid >> 6;
    const int bm = blockIdx.x * 128;
    const int bn = blockIdx.y * 128;
    const int wm = (wv & 1) * 64;
    const int wn = (wv >> 1) * 64;
    const int lr = lane & 15;
    const int lq = lane >> 4;

    const int r0  = tid >> 2;          // 0..63
    const int cc8 = (tid & 3) * 8;

    const bf16* Aps[3] = {A0, A1, A2};
    const bf16* Wps[3] = {W0, W1l, W2l};

    f32x4 acc[4][4];
#pragma unroll
    for (int i = 0; i < 4; i++)
#pragma unroll
        for (int j = 0; j < 4; j++) acc[i][j] = f32x4{0.f, 0.f, 0.f, 0.f};

    constexpr int PI[6] = {0, 0, 1, 1, 0, 2};
    constexpr int PJ[6] = {0, 1, 0, 1, 2, 0};

    for (int k0 = 0; k0 < K; k0 += 32) {
#pragma unroll
        for (int l = 0; l < 3; l++) {
            const bf16* ga = Aps[l] + (size_t)(bm + r0) * K + k0 + cc8;
            const bf16* gw = Wps[l] + (size_t)(bn + r0) * K + k0 + cc8;
            gload16(ga,                  &As[l][r0][cc8]);
            gload16(ga + (size_t)64 * K, &As[l][r0 + 64][cc8]);
            gload16(gw,                  &Ws[l][r0][cc8]);
            gload16(gw + (size_t)64 * K, &Ws[l][r0 + 64][cc8]);
        }
        __syncthreads();

        bf16x8 af[3][4], bfr[3][4];
#pragma unroll
        for (int i = 0; i < 4; i++) {
            af[0][i] = *(const bf16x8*)&As[0][wm + i * 16 + lr][lq * 8];
            af[1][i] = *(const bf16x8*)&As[1][wm + i * 16 + lr][lq * 8];
            af[2][i] = *(const bf16x8*)&As[2][wm + i * 16 + lr][lq * 8];
        }
#pragma unroll
        for (int j = 0; j < 4; j++) {
            bfr[0][j] = *(const bf16x8*)&Ws[0][wn + j * 16 + lr][lq * 8];
            bfr[1][j] = *(const bf16x8*)&Ws[1][wn + j * 16 + lr][lq * 8];
            bfr[2][j] = *(const bf16x8*)&Ws[2][wn + j * 16 + lr][lq * 8];
        }
#pragma unroll
        for (int p = 0; p < 6; p++)
#pragma unroll
            for (int i = 0; i < 4; i++)
#pragma unroll
                for (int j = 0; j < 4; j++)
                    acc[i][j] = __builtin_amdgcn_mfma_f32_16x16x32_bf16(
                        af[PI[p]][i], bfr[PJ[p]][j], acc[i][j], 0, 0, 0);
        __syncthreads();
    }
#pragma unroll
    for (int i = 0; i < 4; i++)
#pragma unroll
        for (int j = 0; j < 4; j++) {
            const int col = bn + wn + j * 16 + lr;
            const float bv = bias[col];
#pragma unroll
            for (int r = 0; r < 4; r++) {
                const int row = bm + wm + i * 16 + lq * 4 + r;
                C[(size_t)row * N + col] = acc[i][j][r] + bv;
            }
        }
}

// ---------------- V: transpose + limb-split into Vt[b][h][d][l] --------------
__global__ __launch_bounds__(256)
void vsplit(const float* __restrict__ Vf, bf16* __restrict__ T0,
            bf16* __restrict__ T1, bf16* __restrict__ T2)
{
    __shared__ __align__(16) bf16 Lt[3][64][72];   // [limb][d][l] (pad 72)
    const int tid = threadIdx.x;
    const int bh  = blockIdx.x;            // b*16 + h
    const int b   = bh >> 4, h = bh & 15;
    const int l0  = blockIdx.y * 64;

    const int dql = tid & 15;              // d-quad index
    const int lrr = tid >> 4;              // 0..15
#pragma unroll
    for (int p = 0; p < 4; p++) {
        const int l = p * 16 + lrr;
        const f32x4 v = *(const f32x4*)(
            Vf + (size_t)(b * LL + l0 + l) * 1024 + h * 64 + dql * 4);
        bf16x4 a, bq, c; split3v(v, a, bq, c);
#pragma unroll
        for (int e = 0; e < 4; e++) {
            Lt[0][dql * 4 + e][l] = a[e];
            Lt[1][dql * 4 + e][l] = bq[e];
            Lt[2][dql * 4 + e][l] = c[e];
        }
    }
    __syncthreads();
    const int d  = tid >> 2;
    const int lc = tid & 3;
    const size_t o = (size_t)bh * 65536 + (size_t)d * 1024 + l0 + lc * 16;
    *(bf16x8*)(T0 + o)     = *(const bf16x8*)&Lt[0][d][lc * 16];
    *(bf16x8*)(T0 + o + 8) = *(const bf16x8*)&Lt[0][d][lc * 16 + 8];
    *(bf16x8*)(T1 + o)     = *(const bf16x8*)&Lt[1][d][lc * 16];
    *(bf16x8*)(T1 + o + 8) = *(const bf16x8*)&Lt[1][d][lc * 16 + 8];
    *(bf16x8*)(T2 + o)     = *(const bf16x8*)&Lt[2][d][lc * 16];
    *(bf16x8*)(T2 + o + 8) = *(const bf16x8*)&Lt[2][d][lc * 16 + 8];
}

// ---------------- flash attention, bf16-limb MFMA, fixed-ref softmax ---------
// R13: double-buffered Ks/Vs, ONE barrier per k-tile. __expf + MFMA row-sum.
__global__ __launch_bounds__(256)
void flash_mfma(float* __restrict__ Qf, const float* __restrict__ Kf,
                const bf16* __restrict__ Vt0, const bf16* __restrict__ Vt1,
                const bf16* __restrict__ Vt2)
{
    __shared__ __align__(16) bf16  Ks[2][3][32][64];  // dbuf [limb][ktok][d]
    __shared__ __align__(16) bf16  Vs[2][3][64][32];  // dbuf [limb][d][ktok]
    __shared__ __align__(16) float Ps[128][32];       // wave-private rows

    const int tid  = threadIdx.x;
    const int lane = tid & 63;
    const int w    = tid >> 6;
    const int lr   = lane & 15;
    const int lq   = lane >> 4;
    const int lr7  = lr & 7;

    const int bid = (int)blockIdx.x;
    const int qb  = (bid >> 3) & 7;
    const int bh  = (bid & 7) * 16 + (bid >> 6);
    const int b   = bh >> 4, h = bh & 15;
    const int q0  = qb * 128;
    const size_t base = (size_t)b * LL * 1024 + (size_t)h * 64;

    // ---- Q fragments: 3 limbs x 2 mi x 2 ks, pre-scaled by 1/8 (exact) ----
    bf16x8 qf[3][2][2];
#pragma unroll
    for (int mi = 0; mi < 2; mi++)
#pragma unroll
        for (int ks = 0; ks < 2; ks++) {
            const float* src = Qf + base +
                (size_t)(q0 + w * 32 + mi * 16 + lr) * 1024 + ks * 32 + lq * 8;
            f32x4 v0 = *(const f32x4*)src;
            f32x4 v1 = *(const f32x4*)(src + 4);
            v0 *= 0.125f; v1 *= 0.125f;
            bf16x4 a0, b0, c0, a1, b1, c1;
            split3v(v0, a0, b0, c0);
            split3v(v1, a1, b1, c1);
            qf[0][mi][ks] = pack8(a0, a1);
            qf[1][mi][ks] = pack8(b0, b1);
            qf[2][mi][ks] = pack8(c0, c1);
        }

    // ---- ones B-fragment for MFMA row-sum ----
    bf16x8 onesf;
#pragma unroll
    for (int e = 0; e < 8; e++) onesf[e] = (bf16)1.0f;

    // ---- staging geometry + prologue prefetch (tile 0) ----
    const int kr  = tid >> 3, kq = tid & 7;          // K: row 0..31, granule 0..7
    const int kpg = kq ^ (kr & 7);                   // phys granule in Ks
    const int vr  = tid >> 2, vg = tid & 3;          // V: d-row 0..63, phys gran
    const int vlg = vg ^ ((vr >> 1) & 3);            // logical granule to fetch
    const float* kbase = Kf + base + (size_t)kr * 1024 + kq * 8;
    const size_t vtb = (size_t)bh * 65536 + (size_t)vr * 1024 + (size_t)vlg * 8;

    f32x4  kp0 = *(const f32x4*)(kbase);
    f32x4  kp1 = *(const f32x4*)(kbase + 4);
    bf16x8 vp0 = *(const bf16x8*)(Vt0 + vtb);
    bf16x8 vp1 = *(const bf16x8*)(Vt1 + vtb);
    bf16x8 vp2 = *(const bf16x8*)(Vt2 + vtb);

    f32x4 acc_l[2];
    f32x4 accO[2][4];
#pragma unroll
    for (int mi = 0; mi < 2; mi++) {
        acc_l[mi] = f32x4{0.f, 0.f, 0.f, 0.f};
#pragma unroll
        for (int nd = 0; nd < 4; nd++) accO[mi][nd] = f32x4{0.f, 0.f, 0.f, 0.f};
    }

    constexpr int PI[6] = {0, 0, 1, 1, 0, 2};
    constexpr int PJ[6] = {0, 1, 0, 1, 2, 0};

    for (int kt = 0; kt < 32; kt++) {
        const int bs = kt & 1;
        // ---- store tile kt into buf[bs] (prev readers of bs done: BAR@kt-1)
        {
            bf16x4 a0, b0, c0, a1, b1, c1;
            split3v(kp0, a0, b0, c0);
            split3v(kp1, a1, b1, c1);
            *(bf16x8*)&Ks[bs][0][kr][kpg * 8] = pack8(a0, a1);
            *(bf16x8*)&Ks[bs][1][kr][kpg * 8] = pack8(b0, b1);
            *(bf16x8*)&Ks[bs][2][kr][kpg * 8] = pack8(c0, c1);
            *(bf16x8*)&Vs[bs][0][vr][vg * 8] = vp0;
            *(bf16x8*)&Vs[bs][1][vr][vg * 8] = vp1;
            *(bf16x8*)&Vs[bs][2][vr][vg * 8] = vp2;
        }
        __syncthreads();                 // tile kt visible (single barrier)
        // ---- prefetch tile kt+1 AFTER barrier: latency hides under compute
        if (kt < 31) {
            const float* ks_ = kbase + (size_t)(kt + 1) * 32 * 1024;
            kp0 = *(const f32x4*)ks_;
            kp1 = *(const f32x4*)(ks_ + 4);
            const size_t vo = vtb + (size_t)(kt + 1) * 32;
            vp0 = *(const bf16x8*)(Vt0 + vo);
            vp1 = *(const bf16x8*)(Vt1 + vo);
            vp2 = *(const bf16x8*)(Vt2 + vo);
        }

        // ---- scores: accS[mi][nj], 48 MFMA ----
        f32x4 accS[2][2];
#pragma unroll
        for (int mi = 0; mi < 2; mi++)
#pragma unroll
            for (int nj = 0; nj < 2; nj++) accS[mi][nj] = f32x4{0.f, 0.f, 0.f, 0.f};
#pragma unroll
        for (int nj = 0; nj < 2; nj++) {
            bf16x8 kfr[3][2];
#pragma unroll
            for (int ks = 0; ks < 2; ks++) {
                const int kg = (ks * 4 + lq) ^ lr7;
                kfr[0][ks] = *(const bf16x8*)&Ks[bs][0][nj * 16 + lr][kg * 8];
                kfr[1][ks] = *(const bf16x8*)&Ks[bs][1][nj * 16 + lr][kg * 8];
                kfr[2][ks] = *(const bf16x8*)&Ks[bs][2][nj * 16 + lr][kg * 8];
            }
#pragma unroll
            for (int p = 0; p < 6; p++)
#pragma unroll
                for (int mi = 0; mi < 2; mi++)
#pragma unroll
                    for (int ks = 0; ks < 2; ks++)
                        accS[mi][nj] = __builtin_amdgcn_mfma_f32_16x16x32_bf16(
                            qf[PI[p]][mi][ks], kfr[PJ[p]][ks], accS[mi][nj], 0, 0, 0);
        }

        // ---- fixed-reference softmax: p = exp-native(s) ----
#pragma unroll
        for (int mi = 0; mi < 2; mi++)
#pragma unroll
            for (int rr = 0; rr < 4; rr++) {
                const float p0 = __expf(accS[mi][0][rr]);
                const float p1 = __expf(accS[mi][1][rr]);
                const int prow = w * 32 + mi * 16 + lq * 4 + rr;
                const int pr7  = prow & 7;
                Ps[prow][(((lr >> 2) ^ pr7) << 2) | (lr & 3)]       = p0;
                Ps[prow][(((4 + (lr >> 2)) ^ pr7) << 2) | (lr & 3)] = p1;
            }

        // ---- P: C-layout -> A-layout via LDS (same-wave, in-order DS) ----
        bf16x8 pf[3][2];
#pragma unroll
        for (int mi = 0; mi < 2; mi++) {
            const int row = w * 32 + mi * 16 + lr;
            const f32x4 v0 = *(const f32x4*)&Ps[row][((2 * lq) ^ lr7) * 4];
            const f32x4 v1 = *(const f32x4*)&Ps[row][((2 * lq + 1) ^ lr7) * 4];
            bf16x4 a0, b0, c0, a1, b1, c1;
            split3v(v0, a0, b0, c0);
            split3v(v1, a1, b1, c1);
            pf[0][mi] = pack8(a0, a1);
            pf[1][mi] = pack8(b0, b1);
            pf[2][mi] = pack8(c0, c1);
        }

        // ---- l via MFMA row-sum: acc_l[mi][rr] += sum_k P[row][k] ----
#pragma unroll
        for (int mi = 0; mi < 2; mi++) {
            acc_l[mi] = __builtin_amdgcn_mfma_f32_16x16x32_bf16(
                pf[0][mi], onesf, acc_l[mi], 0, 0, 0);
            acc_l[mi] = __builtin_amdgcn_mfma_f32_16x16x32_bf16(
                pf[1][mi], onesf, acc_l[mi], 0, 0, 0);
            acc_l[mi] = __builtin_amdgcn_mfma_f32_16x16x32_bf16(
                pf[2][mi], onesf, acc_l[mi], 0, 0, 0);
        }

        // ---- PV: accO += P*V, 48 MFMA ----
        const int vgp = lq ^ ((lr >> 1) & 3);
#pragma unroll
        for (int nd = 0; nd < 4; nd++) {
            bf16x8 vfr[3];
            vfr[0] = *(const bf16x8*)&Vs[bs][0][nd * 16 + lr][vgp * 8];
            vfr[1] = *(const bf16x8*)&Vs[bs][1][nd * 16 + lr][vgp * 8];
            vfr[2] = *(const bf16x8*)&Vs[bs][2][nd * 16 + lr][vgp * 8];
#pragma unroll
            for (int p = 0; p < 6; p++)
#pragma unroll
                for (int mi = 0; mi < 2; mi++)
                    accO[mi][nd] = __builtin_amdgcn_mfma_f32_16x16x32_bf16(
                        pf[PI[p]][mi], vfr[PJ[p]], accO[mi][nd], 0, 0, 0);
        }
    }

    // ---- epilogue: Z = accO / l, in-place over Qf ----
#pragma unroll
    for (int mi = 0; mi < 2; mi++) {
        float inv[4];
#pragma unroll
        for (int rr = 0; rr < 4; rr++) inv[rr] = 1.f / acc_l[mi][rr];
#pragma unroll
        for (int nd = 0; nd < 4; nd++)
#pragma unroll
            for (int rr = 0; rr < 4; rr++)
                Qf[base + (size_t)(q0 + w * 32 + mi * 16 + lq * 4 + rr) * 1024 +
                   nd * 16 + lr] = accO[mi][nd][rr] * inv[rr];
    }
}

// ---------------- LayerNorm(qx + att) ----------------------------------------
__global__ __launch_bounds__(256)
void ln_kernel(const float* __restrict__ qx, const float* __restrict__ att,
               const float* __restrict__ w, const float* __restrict__ bch,
               float* __restrict__ zn)
{
    const int row = blockIdx.x, tid = threadIdx.x;
    const size_t off = (size_t)row * 1024 + tid * 4;
    const f32x4 q4 = *(const f32x4*)(qx + off);
    const f32x4 a4 = *(const f32x4*)(att + off);
    float x[4];
#pragma unroll
    for (int i = 0; i < 4; i++) x[i] = q4[i] + a4[i];

    __shared__ float red[8];
    float part = x[0] + x[1] + x[2] + x[3];
#pragma unroll
    for (int d = 1; d < 64; d <<= 1) part += __shfl_xor(part, d);
    if ((tid & 63) == 0) red[tid >> 6] = part;
    __syncthreads();
    const float mu = (red[0] + red[1] + red[2] + red[3]) * (1.f / 1024.f);

    float p2 = 0.f;
#pragma unroll
    for (int i = 0; i < 4; i++) { const float d = x[i] - mu; p2 += d * d; }
#pragma unroll
    for (int d = 1; d < 64; d <<= 1) p2 += __shfl_xor(p2, d);
    if ((tid & 63) == 0) red[4 + (tid >> 6)] = p2;
    __syncthreads();
    const float var  = (red[4] + red[5] + red[6] + red[7]) * (1.f / 1024.f);
    const float rstd = 1.f / sqrtf(var + 1e-5f);

    const f32x4 w4 = *(const f32x4*)(w + tid * 4);
    const f32x4 b4 = *(const f32x4*)(bch + tid * 4);
    f32x4 out;
#pragma unroll
    for (int i = 0; i < 4; i++)
        out[i] = (x[i] - mu) * rstd * w4[i] + b4[i];
    *(f32x4*)(zn + off) = out;
}

// ---------------- router: logits + first-max argmax --------------------------
__global__ __launch_bounds__(64)
void router_kernel(const float* __restrict__ zn, const float* __restrict__ Wsw,
                   const float* __restrict__ bsw, int* __restrict__ routes)
{
    const int t = blockIdx.x, lane = threadIdx.x;
    const float* x = zn + (size_t)t * 1024;
    float acc[16];
#pragma unroll
    for (int e = 0; e < 16; e++) acc[e] = 0.f;
    for (int ii = 0; ii < 16; ii++) {
        const float xv = x[lane + 64 * ii];
#pragma unroll
        for (int e = 0; e < 16; e++)
            acc[e] += xv * Wsw[e * 1024 + lane + 64 * ii];
    }
#pragma unroll
    for (int e = 0; e < 16; e++)
#pragma unroll
        for (int d = 1; d < 64; d <<= 1) acc[e] += __shfl_xor(acc[e], d);
    if (lane == 0) {
        float best = acc[0] + bsw[0];
        int bi = 0;
#pragma unroll
        for (int e = 1; e < 16; e++) {
            const float lg = acc[e] + bsw[e];
            if (lg > best) { best = lg; bi = e; }   // strict > == np first-max
        }
        routes[t] = bi;
    }
}

// ---------------- capacity scan ----------------------------------------------
__global__ __launch_bounds__(1024)
void route_scan(const int* __restrict__ routes, int* __restrict__ slot_of_token,
                int* __restrict__ token_of_slot)
{
    const int wv = threadIdx.x >> 6;      // expert id
    const int lane = threadIdx.x & 63;
    int cnt = 0;
    for (int c = 0; c < NTOK / 64; c++) {
        const int tok = c * 64 + lane;
        const bool match = (routes[tok] == wv);
        const unsigned long long mask = __ballot(match);
        const int pos = cnt + __popcll(mask & ((1ull << lane) - 1ull));
        if (match) {
            if (pos < CAP) {
                slot_of_token[tok] = wv * CAP + pos;
                token_of_slot[wv * CAP + pos] = tok;
            } else slot_of_token[tok] = -1;
        }
        cnt += __popcll(mask);
    }
    const int filled = cnt < CAP ? cnt : CAP;
    for (int s2 = filled + lane; s2 < CAP; s2 += 64)
        token_of_slot[wv * CAP + s2] = -1;
}

// ---------------- expert FFN (8 slots/block: W traffic /8) -------------------
__global__ __launch_bounds__(64)
void ffn1(const float* __restrict__ zn, const int* __restrict__ token_of_slot,
          const float* __restrict__ W1, const float* __restrict__ b1,
          float* __restrict__ hbuf)
{
    const int s0 = blockIdx.x * 8, lane = threadIdx.x;
    const int e = s0 >> 8;
    int tk[8];
    const float* xs[8];
    float acc[8];
#pragma unroll
    for (int u = 0; u < 8; u++) {
        tk[u] = token_of_slot[s0 + u];
        xs[u] = zn + (size_t)(tk[u] < 0 ? 0 : tk[u]) * 1024;
        acc[u] = 0.f;
    }
    const float* w = W1 + (size_t)e * CC * NHID + lane;
#pragma unroll 4
    for (int i = 0; i < 1024; i++) {
        const float wv = w[(size_t)i * NHID];
#pragma unroll
        for (int u = 0; u < 8; u++) acc[u] += xs[u][i] * wv;
    }
    const float bv = b1[e * NHID + lane];
#pragma unroll
    for (int u = 0; u < 8; u++)
        if (tk[u] >= 0)
            hbuf[(size_t)(s0 + u) * NHID + lane] = fmaxf(acc[u] + bv, 0.f);
}

__global__ __launch_bounds__(256)
void ffn2(const float* __restrict__ hbuf, const int* __restrict__ token_of_slot,
          const float* __restrict__ W2, const float* __restrict__ b2,
          float* __restrict__ ybuf)
{
    const int s0 = blockIdx.x * 8, tid = threadIdx.x;
    const int e = s0 >> 8;
    const int c0 = tid * 4;
    const float* w = W2 + (size_t)e * NHID * CC + c0;
    const f32x4 b4 = *(const f32x4*)(b2 + e * CC + c0);
    int tk[8];
    f32x4 a[8];
#pragma unroll
    for (int u = 0; u < 8; u++) { tk[u] = token_of_slot[s0 + u]; a[u] = b4; }
#pragma unroll 4
    for (int k = 0; k < NHID; k++) {
        const f32x4 w4 = *(const f32x4*)(w + (size_t)k * CC);
#pragma unroll
        for (int u = 0; u < 8; u++) {
            const float hv = hbuf[(size_t)(s0 + u) * NHID + k];
            a[u][0] += hv * w4[0]; a[u][1] += hv * w4[1];
            a[u][2] += hv * w4[2]; a[u][3] += hv * w4[3];
        }
    }
#pragma unroll
    for (int u = 0; u < 8; u++)
        if (tk[u] >= 0)
            *(f32x4*)(ybuf + (size_t)(s0 + u) * 1024 + c0) = a[u];
}

// ---------------- final: out = zn + (kept ? y : zn); mask = 1 ----------------
__global__ __launch_bounds__(256)
void assemble(const float* __restrict__ zn, const float* __restrict__ ybuf,
              const int* __restrict__ slot_of_token, float* __restrict__ out,
              float* __restrict__ maskout)
{
    const int tok = blockIdx.x, tid = threadIdx.x;
    const int slot = slot_of_token[tok];
    const size_t off = (size_t)tok * 1024 + tid * 4;
    const f32x4 z4 = *(const f32x4*)(zn + off);
    f32x4 m4;
    if (slot >= 0) m4 = *(const f32x4*)(ybuf + (size_t)slot * 1024 + tid * 4);
    else           m4 = z4;
    f32x4 o;
#pragma unroll
    for (int i = 0; i < 4; i++) o[i] = z4[i] + m4[i];
    *(f32x4*)(out + off) = o;
    if (tid == 0) maskout[tok] = 1.0f;
}

// ---------------- launch -----------------------------------------------------
extern "C" void kernel_launch(void* const* d_in, const int* in_sizes, int n_in,
                              void* d_out, int out_size, void* d_ws, size_t ws_size,
                              hipStream_t stream)
{
    (void)out_size; (void)ws_size;
    const float* qx = (const float*)d_in[0];
    const float* kx = (const float*)d_in[1];
    const float* vx = (const float*)d_in[2];
    int wbase = 4;
    if (n_in >= 4 && in_sizes[3] != NB * LL) wbase = 3;
    const float* WQ   = (const float*)d_in[wbase + 0];
    const float* bQ   = (const float*)d_in[wbase + 1];
    const float* WK   = (const float*)d_in[wbase + 2];
    const float* bK   = (const float*)d_in[wbase + 3];
    const float* WV   = (const float*)d_in[wbase + 4];
    const float* bV   = (const float*)d_in[wbase + 5];
    const float* WO   = (const float*)d_in[wbase + 6];
    const float* bO   = (const float*)d_in[wbase + 7];
    const float* ln1w = (const float*)d_in[wbase + 8];
    const float* ln1b = (const float*)d_in[wbase + 9];
    const float* Wsw  = (const float*)d_in[wbase + 10];
    const float* bsw  = (const float*)d_in[wbase + 11];
    const float* W1   = (const float*)d_in[wbase + 12];
    const float* b1   = (const float*)d_in[wbase + 13];
    const float* W2   = (const float*)d_in[wbase + 14];
    const float* b2   = (const float*)d_in[wbase + 15];

    char* D   = (char*)d_out;
    char* wsb = (char*)d_ws;

    // Buffer plan (ws proven to 54 MiB; d_out = 96 MiB f32 + mask):
    //   Qbuf(=Z) @ ws0..32 | la2 @ ws32..48 | lw @ ws48..54
    //   la0 @ D0..16 | la1 @ D16..32 | Kbuf @ D32..64 | Vbuf @ D64..96
    // During flash: Vt limbs (3 x 16 MiB) live in the la0/la1/la2 regions
    // (dead between the V gemm and the out-proj split).
    float* Qbuf = (float*)(wsb);
    bf16*  la0  = (bf16*)(D);
    bf16*  la1  = (bf16*)(D + (size_t)16 * MB);
    bf16*  la2  = (bf16*)(wsb + (size_t)32 * MB);
    bf16*  lw0  = (bf16*)(wsb + (size_t)48 * MB);
    bf16*  lw1  = (bf16*)(wsb + (size_t)50 * MB);
    bf16*  lw2  = (bf16*)(wsb + (size_t)52 * MB);
    float* Kbuf = (float*)(D + (size_t)32 * MB);
    float* Vbuf = (float*)(D + (size_t)64 * MB);

    const dim3 gblk(NTOK / 128, CC / 128, 1);
    const int GA = NTOK * 1024 / 1024;   // 8192 blocks
    const int GW = CC * 1024 / 1024;     // 1024 blocks

    split3<<<GA, 256, 0, stream>>>(qx, la0, la1, la2);
    split3<<<GW, 256, 0, stream>>>(WQ, lw0, lw1, lw2);
    gemm_limb6<<<gblk, 256, 0, stream>>>(la0, la1, la2, lw0, lw1, lw2, bQ, Qbuf, NTOK, CC, CC);
    split3<<<GA, 256, 0, stream>>>(kx, la0, la1, la2);
    split3<<<GW, 256, 0, stream>>>(WK, lw0, lw1, lw2);
    gemm_limb6<<<gblk, 256, 0, stream>>>(la0, la1, la2, lw0, lw1, lw2, bK, Kbuf, NTOK, CC, CC);
    split3<<<GA, 256, 0, stream>>>(vx, la0, la1, la2);
    split3<<<GW, 256, 0, stream>>>(WV, lw0, lw1, lw2);
    gemm_limb6<<<gblk, 256, 0, stream>>>(la0, la1, la2, lw0, lw1, lw2, bV, Vbuf, NTOK, CC, CC);

    // V -> transposed bf16 limbs (la regions are dead here)
    bf16* Vt0 = la0;
    bf16* Vt1 = la1;
    bf16* Vt2 = la2;
    vsplit<<<dim3(128, 16), 256, 0, stream>>>(Vbuf, Vt0, Vt1, Vt2);

    flash_mfma<<<1024, 256, 0, stream>>>(Qbuf, Kbuf, Vt0, Vt1, Vt2);   // Z -> Qbuf in-place

    // out-proj: att = z @ WO^T + bO   (z = Qbuf; la/Vt dead -> reuse for z limbs)
    split3<<<GA, 256, 0, stream>>>(Qbuf, la0, la1, la2);
    split3<<<GW, 256, 0, stream>>>(WO, lw0, lw1, lw2);
    float* attbuf = Kbuf;   // Kf32 dead after flash
    gemm_limb6<<<gblk, 256, 0, stream>>>(la0, la1, la2, lw0, lw1, lw2, bO, attbuf, NTOK, CC, CC);

    float* znbuf = Vbuf;    // Vf32 dead after vsplit
    ln_kernel<<<NTOK, 256, 0, stream>>>(qx, attbuf, ln1w, ln1b, znbuf);

    // MoE scratch (all dead regions post out-proj)
    int*   routes        = (int*)(wsb + (size_t)32 * MB);
    int*   slot_of_token = (int*)(wsb + (size_t)32 * MB + 64 * 1024);
    int*   token_of_slot = (int*)(wsb + (size_t)32 * MB + 128 * 1024);
    float* hbuf          = (float*)(wsb + (size_t)33 * MB);
    float* ybuf          = (float*)(wsb + (size_t)34 * MB);   // 16 MiB -> ws34..50

    router_kernel<<<NTOK, 64, 0, stream>>>(znbuf, Wsw, bsw, routes);
    route_scan<<<1, 1024, 0, stream>>>(routes, slot_of_token, token_of_slot);
    ffn1<<<NE * CAP / 8, 64, 0, stream>>>(znbuf, token_of_slot, W1, b1, hbuf);
    ffn2<<<NE * CAP / 8, 256, 0, stream>>>(hbuf, token_of_slot, W2, b2, ybuf);

    assemble<<<NTOK, 256, 0, stream>>>(znbuf, ybuf, slot_of_token, (float*)d_out,
                                       (float*)d_out + (size_t)3 * NTOK * 1024);

    // passthrough outputs (overwrite dead attbuf/znbuf regions)
    hipMemcpyAsync(D + (size_t)32 * MB, (const void*)kx,
                   (size_t)NTOK * 1024 * 4, hipMemcpyDeviceToDevice, stream);
    hipMemcpyAsync(D + (size_t)64 * MB, (const void*)vx,
                   (size_t)NTOK * 1024 * 4, hipMemcpyDeviceToDevice, stream);
}

// Round 10
// 1036.561 us; speedup vs baseline: 1.0008x; 1.0008x over previous
//
#include <hip/hip_runtime.h>

// Transformer block + switch-MoE, MI355X gfx950. ALL I/O FLOAT32.
// R14: consolidation + flash occupancy.
//  - ffn1/ffn2 REVERTED to R12 per-slot form (R13's 8-slot blocking cut
//    ffn to 2 waves/CU: -40us regression; W matrices were already L2-resident).
//  - flash: Q-tile 128->64 rows, grid 1024->2048. Halves per-wave register
//    state (qf/accO/acc_l) -> register-capped occupancy should double.
//    Same limb bits, same MFMA pass order, same Ps swizzle (mi-dim removed).
//    Single-buffer staging (R13 dbuf was null: 194->195).
//  - mask write stays folded into assemble.
// History: R12 997us (flash 194: __expf + MFMA row-sum + fixed-ref softmax);
// gemms ~145 each (R6 m97-class structure; R8/R9 pipelining nulls).

typedef __bf16 bf16;
typedef __bf16 bf16x4 __attribute__((ext_vector_type(4)));
typedef __bf16 bf16x8 __attribute__((ext_vector_type(8)));
typedef float  f32x4  __attribute__((ext_vector_type(4)));

#define NB    8
#define LL    1024
#define CC    1024
#define NH    16
#define DKD   64
#define NE    16
#define NHID  64
#define CAP   256
#define NTOK  (NB*LL)          // 8192
#define MB    (1024*1024)

__device__ __forceinline__ void gload16(const bf16* g, bf16* l)
{
    __builtin_amdgcn_global_load_lds(
        (const __attribute__((address_space(1))) void*)g,
        (__attribute__((address_space(3))) void*)l, 16, 0, 0);
}

__device__ inline void split3v(const f32x4 v, bf16x4& a, bf16x4& b, bf16x4& c)
{
#pragma unroll
    for (int k = 0; k < 4; k++) {
        const float x  = v[k];
        const bf16  hi = (bf16)x;
        const float r1 = x - (float)hi;
        const bf16  md = (bf16)r1;
        const float r2 = r1 - (float)md;
        a[k] = hi; b[k] = md; c[k] = (bf16)r2;
    }
}

__device__ inline bf16x8 pack8(const bf16x4 a, const bf16x4 b)
{
    bf16x8 r;
#pragma unroll
    for (int e = 0; e < 4; e++) { r[e] = a[e]; r[4 + e] = b[e]; }
    return r;
}

// ---------------- split f32 -> 3 bf16 limbs (hi, mid, lo) --------------------
__global__ __launch_bounds__(256)
void split3(const float* __restrict__ z, bf16* __restrict__ z1,
            bf16* __restrict__ z2, bf16* __restrict__ z3)
{
    const size_t i = ((size_t)blockIdx.x * 256 + threadIdx.x) * 4;
    const f32x4 v = *(const f32x4*)(z + i);
    bf16x4 a, b, c;
    split3v(v, a, b, c);
    *(bf16x4*)(z1 + i) = a;
    *(bf16x4*)(z2 + i) = b;
    *(bf16x4*)(z3 + i) = c;
}

// ------- GEMM: C[M,N] = A[M,K] @ W[N,K]^T + bias, A/W as 3 bf16 limbs -------
// R6 structure (verified, best measured): LDS-staged, 128x128 tile, BK=32,
// 4 waves (64x64 each), global_load_lds width=16.
__global__ __launch_bounds__(256)
void gemm_limb6(const bf16* __restrict__ A0, const bf16* __restrict__ A1,
                const bf16* __restrict__ A2,
                const bf16* __restrict__ W0, const bf16* __restrict__ W1l,
                const bf16* __restrict__ W2l,
                const float* __restrict__ bias, float* __restrict__ C,
                int M, int N, int K)
{
    __shared__ __align__(16) bf16 As[3][128][32];
    __shared__ __align__(16) bf16 Ws[3][128][32];

    const int tid  = threadIdx.x;
    const int lane = tid & 63;
    const int wv   = tid >> 6;
    const int bm = blockIdx.x * 128;
    const int bn = blockIdx.y * 128;
    const int wm = (wv & 1) * 64;
    const int wn = (wv >> 1) * 64;
    const int lr = lane & 15;
    const int lq = lane >> 4;

    const int r0  = tid >> 2;          // 0..63
    const int cc8 = (tid & 3) * 8;

    const bf16* Aps[3] = {A0, A1, A2};
    const bf16* Wps[3] = {W0, W1l, W2l};

    f32x4 acc[4][4];
#pragma unroll
    for (int i = 0; i < 4; i++)
#pragma unroll
        for (int j = 0; j < 4; j++) acc[i][j] = f32x4{0.f, 0.f, 0.f, 0.f};

    constexpr int PI[6] = {0, 0, 1, 1, 0, 2};
    constexpr int PJ[6] = {0, 1, 0, 1, 2, 0};

    for (int k0 = 0; k0 < K; k0 += 32) {
#pragma unroll
        for (int l = 0; l < 3; l++) {
            const bf16* ga = Aps[l] + (size_t)(bm + r0) * K + k0 + cc8;
            const bf16* gw = Wps[l] + (size_t)(bn + r0) * K + k0 + cc8;
            gload16(ga,                  &As[l][r0][cc8]);
            gload16(ga + (size_t)64 * K, &As[l][r0 + 64][cc8]);
            gload16(gw,                  &Ws[l][r0][cc8]);
            gload16(gw + (size_t)64 * K, &Ws[l][r0 + 64][cc8]);
        }
        __syncthreads();

        bf16x8 af[3][4], bfr[3][4];
#pragma unroll
        for (int i = 0; i < 4; i++) {
            af[0][i] = *(const bf16x8*)&As[0][wm + i * 16 + lr][lq * 8];
            af[1][i] = *(const bf16x8*)&As[1][wm + i * 16 + lr][lq * 8];
            af[2][i] = *(const bf16x8*)&As[2][wm + i * 16 + lr][lq * 8];
        }
#pragma unroll
        for (int j = 0; j < 4; j++) {
            bfr[0][j] = *(const bf16x8*)&Ws[0][wn + j * 16 + lr][lq * 8];
            bfr[1][j] = *(const bf16x8*)&Ws[1][wn + j * 16 + lr][lq * 8];
            bfr[2][j] = *(const bf16x8*)&Ws[2][wn + j * 16 + lr][lq * 8];
        }
#pragma unroll
        for (int p = 0; p < 6; p++)
#pragma unroll
            for (int i = 0; i < 4; i++)
#pragma unroll
                for (int j = 0; j < 4; j++)
                    acc[i][j] = __builtin_amdgcn_mfma_f32_16x16x32_bf16(
                        af[PI[p]][i], bfr[PJ[p]][j], acc[i][j], 0, 0, 0);
        __syncthreads();
    }
#pragma unroll
    for (int i = 0; i < 4; i++)
#pragma unroll
        for (int j = 0; j < 4; j++) {
            const int col = bn + wn + j * 16 + lr;
            const float bv = bias[col];
#pragma unroll
            for (int r = 0; r < 4; r++) {
                const int row = bm + wm + i * 16 + lq * 4 + r;
                C[(size_t)row * N + col] = acc[i][j][r] + bv;
            }
        }
}

// ---------------- V: transpose + limb-split into Vt[b][h][d][l] --------------
__global__ __launch_bounds__(256)
void vsplit(const float* __restrict__ Vf, bf16* __restrict__ T0,
            bf16* __restrict__ T1, bf16* __restrict__ T2)
{
    __shared__ __align__(16) bf16 Lt[3][64][72];   // [limb][d][l] (pad 72)
    const int tid = threadIdx.x;
    const int bh  = blockIdx.x;            // b*16 + h
    const int b   = bh >> 4, h = bh & 15;
    const int l0  = blockIdx.y * 64;

    const int dql = tid & 15;              // d-quad index
    const int lrr = tid >> 4;              // 0..15
#pragma unroll
    for (int p = 0; p < 4; p++) {
        const int l = p * 16 + lrr;
        const f32x4 v = *(const f32x4*)(
            Vf + (size_t)(b * LL + l0 + l) * 1024 + h * 64 + dql * 4);
        bf16x4 a, bq, c; split3v(v, a, bq, c);
#pragma unroll
        for (int e = 0; e < 4; e++) {
            Lt[0][dql * 4 + e][l] = a[e];
            Lt[1][dql * 4 + e][l] = bq[e];
            Lt[2][dql * 4 + e][l] = c[e];
        }
    }
    __syncthreads();
    const int d  = tid >> 2;
    const int lc = tid & 3;
    const size_t o = (size_t)bh * 65536 + (size_t)d * 1024 + l0 + lc * 16;
    *(bf16x8*)(T0 + o)     = *(const bf16x8*)&Lt[0][d][lc * 16];
    *(bf16x8*)(T0 + o + 8) = *(const bf16x8*)&Lt[0][d][lc * 16 + 8];
    *(bf16x8*)(T1 + o)     = *(const bf16x8*)&Lt[1][d][lc * 16];
    *(bf16x8*)(T1 + o + 8) = *(const bf16x8*)&Lt[1][d][lc * 16 + 8];
    *(bf16x8*)(T2 + o)     = *(const bf16x8*)&Lt[2][d][lc * 16];
    *(bf16x8*)(T2 + o + 8) = *(const bf16x8*)&Lt[2][d][lc * 16 + 8];
}

// ---------------- flash attention, bf16-limb MFMA, fixed-ref softmax ---------
// R14: 64-row Q tiles (grid 2048), wave = 16 q-rows. Halved register state
// -> doubled register-capped occupancy. Single-buffer staging (R12 form).
__global__ __launch_bounds__(256)
void flash_mfma(float* __restrict__ Qf, const float* __restrict__ Kf,
                const bf16* __restrict__ Vt0, const bf16* __restrict__ Vt1,
                const bf16* __restrict__ Vt2)
{
    __shared__ __align__(16) bf16  Ks[3][32][64];   // [limb][ktok][d], swizzled
    __shared__ __align__(16) bf16  Vs[3][64][32];   // [limb][d][ktok], swizzled
    __shared__ __align__(16) float Ps[64][32];      // wave-private rows

    const int tid  = threadIdx.x;
    const int lane = tid & 63;
    const int w    = tid >> 6;
    const int lr   = lane & 15;
    const int lq   = lane >> 4;
    const int lr7  = lr & 7;

    // bijective decode: bid = xcd(3b) | qb(4b) | bhhi(4b)
    const int bid = (int)blockIdx.x;
    const int qb  = (bid >> 3) & 15;
    const int bh  = (bid & 7) * 16 + (bid >> 7);
    const int b   = bh >> 4, h = bh & 15;
    const int q0  = qb * 64;
    const size_t base = (size_t)b * LL * 1024 + (size_t)h * 64;

    // ---- Q fragments: 3 limbs x 2 ks, row = q0 + w*16 + lr, scaled 1/8 ----
    bf16x8 qf[3][2];
#pragma unroll
    for (int ks = 0; ks < 2; ks++) {
        const float* src = Qf + base +
            (size_t)(q0 + w * 16 + lr) * 1024 + ks * 32 + lq * 8;
        f32x4 v0 = *(const f32x4*)src;
        f32x4 v1 = *(const f32x4*)(src + 4);
        v0 *= 0.125f; v1 *= 0.125f;
        bf16x4 a0, b0, c0, a1, b1, c1;
        split3v(v0, a0, b0, c0);
        split3v(v1, a1, b1, c1);
        qf[0][ks] = pack8(a0, a1);
        qf[1][ks] = pack8(b0, b1);
        qf[2][ks] = pack8(c0, c1);
    }

    // ---- ones B-fragment for MFMA row-sum ----
    bf16x8 onesf;
#pragma unroll
    for (int e = 0; e < 8; e++) onesf[e] = (bf16)1.0f;

    // ---- staging geometry + prologue prefetch (tile 0) ----
    const int kr  = tid >> 3, kq = tid & 7;          // K: row 0..31, granule 0..7
    const int kpg = kq ^ (kr & 7);                   // phys granule in Ks
    const int vr  = tid >> 2, vg = tid & 3;          // V: d-row 0..63, phys gran
    const int vlg = vg ^ ((vr >> 1) & 3);            // logical granule to fetch
    const float* kbase = Kf + base + (size_t)kr * 1024 + kq * 8;
    const size_t vtb = (size_t)bh * 65536 + (size_t)vr * 1024 + (size_t)vlg * 8;

    f32x4  kp0 = *(const f32x4*)(kbase);
    f32x4  kp1 = *(const f32x4*)(kbase + 4);
    bf16x8 vp0 = *(const bf16x8*)(Vt0 + vtb);
    bf16x8 vp1 = *(const bf16x8*)(Vt1 + vtb);
    bf16x8 vp2 = *(const bf16x8*)(Vt2 + vtb);

    f32x4 acc_l = f32x4{0.f, 0.f, 0.f, 0.f};
    f32x4 accO[4];
#pragma unroll
    for (int nd = 0; nd < 4; nd++) accO[nd] = f32x4{0.f, 0.f, 0.f, 0.f};

    constexpr int PI[6] = {0, 0, 1, 1, 0, 2};
    constexpr int PJ[6] = {0, 1, 0, 1, 2, 0};

    for (int kt = 0; kt < 32; kt++) {
        __syncthreads();                 // all waves done reading prev tile
        {
            bf16x4 a0, b0, c0, a1, b1, c1;
            split3v(kp0, a0, b0, c0);
            split3v(kp1, a1, b1, c1);
            *(bf16x8*)&Ks[0][kr][kpg * 8] = pack8(a0, a1);
            *(bf16x8*)&Ks[1][kr][kpg * 8] = pack8(b0, b1);
            *(bf16x8*)&Ks[2][kr][kpg * 8] = pack8(c0, c1);
            *(bf16x8*)&Vs[0][vr][vg * 8] = vp0;
            *(bf16x8*)&Vs[1][vr][vg * 8] = vp1;
            *(bf16x8*)&Vs[2][vr][vg * 8] = vp2;
        }
        __syncthreads();                 // tile kt visible
        if (kt < 31) {
            const float* ks_ = kbase + (size_t)(kt + 1) * 32 * 1024;
            kp0 = *(const f32x4*)ks_;
            kp1 = *(const f32x4*)(ks_ + 4);
            const size_t vo = vtb + (size_t)(kt + 1) * 32;
            vp0 = *(const bf16x8*)(Vt0 + vo);
            vp1 = *(const bf16x8*)(Vt1 + vo);
            vp2 = *(const bf16x8*)(Vt2 + vo);
        }

        // ---- scores: accS[nj], 24 MFMA ----
        f32x4 accS[2];
#pragma unroll
        for (int nj = 0; nj < 2; nj++) accS[nj] = f32x4{0.f, 0.f, 0.f, 0.f};
#pragma unroll
        for (int nj = 0; nj < 2; nj++) {
            bf16x8 kfr[3][2];
#pragma unroll
            for (int ks = 0; ks < 2; ks++) {
                const int kg = (ks * 4 + lq) ^ lr7;
                kfr[0][ks] = *(const bf16x8*)&Ks[0][nj * 16 + lr][kg * 8];
                kfr[1][ks] = *(const bf16x8*)&Ks[1][nj * 16 + lr][kg * 8];
                kfr[2][ks] = *(const bf16x8*)&Ks[2][nj * 16 + lr][kg * 8];
            }
#pragma unroll
            for (int p = 0; p < 6; p++)
#pragma unroll
                for (int ks = 0; ks < 2; ks++)
                    accS[nj] = __builtin_amdgcn_mfma_f32_16x16x32_bf16(
                        qf[PI[p]][ks], kfr[PJ[p]][ks], accS[nj], 0, 0, 0);
        }

        // ---- fixed-reference softmax: p = exp-native(s) ----
#pragma unroll
        for (int rr = 0; rr < 4; rr++) {
            const float p0 = __expf(accS[0][rr]);
            const float p1 = __expf(accS[1][rr]);
            const int prow = w * 16 + lq * 4 + rr;
            const int pr7  = prow & 7;
            Ps[prow][(((lr >> 2) ^ pr7) << 2) | (lr & 3)]       = p0;
            Ps[prow][(((4 + (lr >> 2)) ^ pr7) << 2) | (lr & 3)] = p1;
        }

        // ---- P: C-layout -> A-layout via LDS (same-wave, in-order DS) ----
        bf16x8 pf[3];
        {
            const int row = w * 16 + lr;
            const f32x4 v0 = *(const f32x4*)&Ps[row][((2 * lq) ^ lr7) * 4];
            const f32x4 v1 = *(const f32x4*)&Ps[row][((2 * lq + 1) ^ lr7) * 4];
            bf16x4 a0, b0, c0, a1, b1, c1;
            split3v(v0, a0, b0, c0);
            split3v(v1, a1, b1, c1);
            pf[0] = pack8(a0, a1);
            pf[1] = pack8(b0, b1);
            pf[2] = pack8(c0, c1);
        }

        // ---- l via MFMA row-sum: acc_l[rr] += sum_k P[row][k] ----
        acc_l = __builtin_amdgcn_mfma_f32_16x16x32_bf16(pf[0], onesf, acc_l, 0, 0, 0);
        acc_l = __builtin_amdgcn_mfma_f32_16x16x32_bf16(pf[1], onesf, acc_l, 0, 0, 0);
        acc_l = __builtin_amdgcn_mfma_f32_16x16x32_bf16(pf[2], onesf, acc_l, 0, 0, 0);

        // ---- PV: accO += P*V, 24 MFMA ----
        const int vgp = lq ^ ((lr >> 1) & 3);
#pragma unroll
        for (int nd = 0; nd < 4; nd++) {
            bf16x8 vfr[3];
            vfr[0] = *(const bf16x8*)&Vs[0][nd * 16 + lr][vgp * 8];
            vfr[1] = *(const bf16x8*)&Vs[1][nd * 16 + lr][vgp * 8];
            vfr[2] = *(const bf16x8*)&Vs[2][nd * 16 + lr][vgp * 8];
#pragma unroll
            for (int p = 0; p < 6; p++)
                accO[nd] = __builtin_amdgcn_mfma_f32_16x16x32_bf16(
                    pf[PI[p]], vfr[PJ[p]], accO[nd], 0, 0, 0);
        }
    }

    // ---- epilogue: Z = accO / l, in-place over Qf ----
    {
        float inv[4];
#pragma unroll
        for (int rr = 0; rr < 4; rr++) inv[rr] = 1.f / acc_l[rr];
#pragma unroll
        for (int nd = 0; nd < 4; nd++)
#pragma unroll
            for (int rr = 0; rr < 4; rr++)
                Qf[base + (size_t)(q0 + w * 16 + lq * 4 + rr) * 1024 +
                   nd * 16 + lr] = accO[nd][rr] * inv[rr];
    }
}

// ---------------- LayerNorm(qx + att) ----------------------------------------
__global__ __launch_bounds__(256)
void ln_kernel(const float* __restrict__ qx, const float* __restrict__ att,
               const float* __restrict__ w, const float* __restrict__ bch,
               float* __restrict__ zn)
{
    const int row = blockIdx.x, tid = threadIdx.x;
    const size_t off = (size_t)row * 1024 + tid * 4;
    const f32x4 q4 = *(const f32x4*)(qx + off);
    const f32x4 a4 = *(const f32x4*)(att + off);
    float x[4];
#pragma unroll
    for (int i = 0; i < 4; i++) x[i] = q4[i] + a4[i];

    __shared__ float red[8];
    float part = x[0] + x[1] + x[2] + x[3];
#pragma unroll
    for (int d = 1; d < 64; d <<= 1) part += __shfl_xor(part, d);
    if ((tid & 63) == 0) red[tid >> 6] = part;
    __syncthreads();
    const float mu = (red[0] + red[1] + red[2] + red[3]) * (1.f / 1024.f);

    float p2 = 0.f;
#pragma unroll
    for (int i = 0; i < 4; i++) { const float d = x[i] - mu; p2 += d * d; }
#pragma unroll
    for (int d = 1; d < 64; d <<= 1) p2 += __shfl_xor(p2, d);
    if ((tid & 63) == 0) red[4 + (tid >> 6)] = p2;
    __syncthreads();
    const float var  = (red[4] + red[5] + red[6] + red[7]) * (1.f / 1024.f);
    const float rstd = 1.f / sqrtf(var + 1e-5f);

    const f32x4 w4 = *(const f32x4*)(w + tid * 4);
    const f32x4 b4 = *(const f32x4*)(bch + tid * 4);
    f32x4 out;
#pragma unroll
    for (int i = 0; i < 4; i++)
        out[i] = (x[i] - mu) * rstd * w4[i] + b4[i];
    *(f32x4*)(zn + off) = out;
}

// ---------------- router: logits + first-max argmax --------------------------
__global__ __launch_bounds__(64)
void router_kernel(const float* __restrict__ zn, const float* __restrict__ Wsw,
                   const float* __restrict__ bsw, int* __restrict__ routes)
{
    const int t = blockIdx.x, lane = threadIdx.x;
    const float* x = zn + (size_t)t * 1024;
    float acc[16];
#pragma unroll
    for (int e = 0; e < 16; e++) acc[e] = 0.f;
    for (int ii = 0; ii < 16; ii++) {
        const float xv = x[lane + 64 * ii];
#pragma unroll
        for (int e = 0; e < 16; e++)
            acc[e] += xv * Wsw[e * 1024 + lane + 64 * ii];
    }
#pragma unroll
    for (int e = 0; e < 16; e++)
#pragma unroll
        for (int d = 1; d < 64; d <<= 1) acc[e] += __shfl_xor(acc[e], d);
    if (lane == 0) {
        float best = acc[0] + bsw[0];
        int bi = 0;
#pragma unroll
        for (int e = 1; e < 16; e++) {
            const float lg = acc[e] + bsw[e];
            if (lg > best) { best = lg; bi = e; }   // strict > == np first-max
        }
        routes[t] = bi;
    }
}

// ---------------- capacity scan ----------------------------------------------
__global__ __launch_bounds__(1024)
void route_scan(const int* __restrict__ routes, int* __restrict__ slot_of_token,
                int* __restrict__ token_of_slot)
{
    const int wv = threadIdx.x >> 6;      // expert id
    const int lane = threadIdx.x & 63;
    int cnt = 0;
    for (int c = 0; c < NTOK / 64; c++) {
        const int tok = c * 64 + lane;
        const bool match = (routes[tok] == wv);
        const unsigned long long mask = __ballot(match);
        const int pos = cnt + __popcll(mask & ((1ull << lane) - 1ull));
        if (match) {
            if (pos < CAP) {
                slot_of_token[tok] = wv * CAP + pos;
                token_of_slot[wv * CAP + pos] = tok;
            } else slot_of_token[tok] = -1;
        }
        cnt += __popcll(mask);
    }
    const int filled = cnt < CAP ? cnt : CAP;
    for (int s2 = filled + lane; s2 < CAP; s2 += 64)
        token_of_slot[wv * CAP + s2] = -1;
}

// ---------------- expert FFN (R12 form, reverted) ----------------------------
__global__ __launch_bounds__(64)
void ffn1(const float* __restrict__ zn, const int* __restrict__ token_of_slot,
          const float* __restrict__ W1, const float* __restrict__ b1,
          float* __restrict__ hbuf)
{
    const int s = blockIdx.x, lane = threadIdx.x;
    const int tok = token_of_slot[s];
    if (tok < 0) return;
    const int e = s >> 8;
    const float* w = W1 + (size_t)e * CC * NHID + lane;
    const float* x = zn + (size_t)tok * 1024;
    float acc = 0.f;
#pragma unroll 8
    for (int i = 0; i < 1024; i++) acc += x[i] * w[(size_t)i * NHID];
    acc += b1[e * NHID + lane];
    hbuf[(size_t)s * NHID + lane] = fmaxf(acc, 0.f);
}

__global__ __launch_bounds__(256)
void ffn2(const float* __restrict__ hbuf, const int* __restrict__ token_of_slot,
          const float* __restrict__ W2, const float* __restrict__ b2,
          float* __restrict__ ybuf)
{
    const int s = blockIdx.x, tid = threadIdx.x;
    const int tok = token_of_slot[s];
    if (tok < 0) return;
    const int e = s >> 8;
    const int c0 = tid * 4;
    const float* w = W2 + (size_t)e * NHID * CC + c0;
    const float* hrow = hbuf + (size_t)s * NHID;
    const f32x4 b4 = *(const f32x4*)(b2 + e * CC + c0);
    float a0 = b4[0], a1 = b4[1], a2 = b4[2], a3 = b4[3];
#pragma unroll 8
    for (int k = 0; k < NHID; k++) {
        const float hv = hrow[k];
        const f32x4 w4 = *(const f32x4*)(w + (size_t)k * CC);
        a0 += hv * w4[0]; a1 += hv * w4[1];
        a2 += hv * w4[2]; a3 += hv * w4[3];
    }
    const f32x4 out = {a0, a1, a2, a3};
    *(f32x4*)(ybuf + (size_t)s * 1024 + c0) = out;
}

// ---------------- final: out = zn + (kept ? y : zn); mask = 1 ----------------
__global__ __launch_bounds__(256)
void assemble(const float* __restrict__ zn, const float* __restrict__ ybuf,
              const int* __restrict__ slot_of_token, float* __restrict__ out,
              float* __restrict__ maskout)
{
    const int tok = blockIdx.x, tid = threadIdx.x;
    const int slot = slot_of_token[tok];
    const size_t off = (size_t)tok * 1024 + tid * 4;
    const f32x4 z4 = *(const f32x4*)(zn + off);
    f32x4 m4;
    if (slot >= 0) m4 = *(const f32x4*)(ybuf + (size_t)slot * 1024 + tid * 4);
    else           m4 = z4;
    f32x4 o;
#pragma unroll
    for (int i = 0; i < 4; i++) o[i] = z4[i] + m4[i];
    *(f32x4*)(out + off) = o;
    if (tid == 0) maskout[tok] = 1.0f;
}

// ---------------- launch -----------------------------------------------------
extern "C" void kernel_launch(void* const* d_in, const int* in_sizes, int n_in,
                              void* d_out, int out_size, void* d_ws, size_t ws_size,
                              hipStream_t stream)
{
    (void)out_size; (void)ws_size;
    const float* qx = (const float*)d_in[0];
    const float* kx = (const float*)d_in[1];
    const float* vx = (const float*)d_in[2];
    int wbase = 4;
    if (n_in >= 4 && in_sizes[3] != NB * LL) wbase = 3;
    const float* WQ   = (const float*)d_in[wbase + 0];
    const float* bQ   = (const float*)d_in[wbase + 1];
    const float* WK   = (const float*)d_in[wbase + 2];
    const float* bK   = (const float*)d_in[wbase + 3];
    const float* WV   = (const float*)d_in[wbase + 4];
    const float* bV   = (const float*)d_in[wbase + 5];
    const float* WO   = (const float*)d_in[wbase + 6];
    const float* bO   = (const float*)d_in[wbase + 7];
    const float* ln1w = (const float*)d_in[wbase + 8];
    const float* ln1b = (const float*)d_in[wbase + 9];
    const float* Wsw  = (const float*)d_in[wbase + 10];
    const float* bsw  = (const float*)d_in[wbase + 11];
    const float* W1   = (const float*)d_in[wbase + 12];
    const float* b1   = (const float*)d_in[wbase + 13];
    const float* W2   = (const float*)d_in[wbase + 14];
    const float* b2   = (const float*)d_in[wbase + 15];

    char* D   = (char*)d_out;
    char* wsb = (char*)d_ws;

    // Buffer plan (ws proven to 54 MiB; d_out = 96 MiB f32 + mask):
    //   Qbuf(=Z) @ ws0..32 | la2 @ ws32..48 | lw @ ws48..54
    //   la0 @ D0..16 | la1 @ D16..32 | Kbuf @ D32..64 | Vbuf @ D64..96
    // During flash: Vt limbs (3 x 16 MiB) live in the la0/la1/la2 regions
    // (dead between the V gemm and the out-proj split).
    float* Qbuf = (float*)(wsb);
    bf16*  la0  = (bf16*)(D);
    bf16*  la1  = (bf16*)(D + (size_t)16 * MB);
    bf16*  la2  = (bf16*)(wsb + (size_t)32 * MB);
    bf16*  lw0  = (bf16*)(wsb + (size_t)48 * MB);
    bf16*  lw1  = (bf16*)(wsb + (size_t)50 * MB);
    bf16*  lw2  = (bf16*)(wsb + (size_t)52 * MB);
    float* Kbuf = (float*)(D + (size_t)32 * MB);
    float* Vbuf = (float*)(D + (size_t)64 * MB);

    const dim3 gblk(NTOK / 128, CC / 128, 1);
    const int GA = NTOK * 1024 / 1024;   // 8192 blocks
    const int GW = CC * 1024 / 1024;     // 1024 blocks

    split3<<<GA, 256, 0, stream>>>(qx, la0, la1, la2);
    split3<<<GW, 256, 0, stream>>>(WQ, lw0, lw1, lw2);
    gemm_limb6<<<gblk, 256, 0, stream>>>(la0, la1, la2, lw0, lw1, lw2, bQ, Qbuf, NTOK, CC, CC);
    split3<<<GA, 256, 0, stream>>>(kx, la0, la1, la2);
    split3<<<GW, 256, 0, stream>>>(WK, lw0, lw1, lw2);
    gemm_limb6<<<gblk, 256, 0, stream>>>(la0, la1, la2, lw0, lw1, lw2, bK, Kbuf, NTOK, CC, CC);
    split3<<<GA, 256, 0, stream>>>(vx, la0, la1, la2);
    split3<<<GW, 256, 0, stream>>>(WV, lw0, lw1, lw2);
    gemm_limb6<<<gblk, 256, 0, stream>>>(la0, la1, la2, lw0, lw1, lw2, bV, Vbuf, NTOK, CC, CC);

    // V -> transposed bf16 limbs (la regions are dead here)
    bf16* Vt0 = la0;
    bf16* Vt1 = la1;
    bf16* Vt2 = la2;
    vsplit<<<dim3(128, 16), 256, 0, stream>>>(Vbuf, Vt0, Vt1, Vt2);

    flash_mfma<<<2048, 256, 0, stream>>>(Qbuf, Kbuf, Vt0, Vt1, Vt2);   // Z -> Qbuf in-place

    // out-proj: att = z @ WO^T + bO   (z = Qbuf; la/Vt dead -> reuse for z limbs)
    split3<<<GA, 256, 0, stream>>>(Qbuf, la0, la1, la2);
    split3<<<GW, 256, 0, stream>>>(WO, lw0, lw1, lw2);
    float* attbuf = Kbuf;   // Kf32 dead after flash
    gemm_limb6<<<gblk, 256, 0, stream>>>(la0, la1, la2, lw0, lw1, lw2, bO, attbuf, NTOK, CC, CC);

    float* znbuf = Vbuf;    // Vf32 dead after vsplit
    ln_kernel<<<NTOK, 256, 0, stream>>>(qx, attbuf, ln1w, ln1b, znbuf);

    // MoE scratch (all dead regions post out-proj)
    int*   routes        = (int*)(wsb + (size_t)32 * MB);
    int*   slot_of_token = (int*)(wsb + (size_t)32 * MB + 64 * 1024);
    int*   token_of_slot = (int*)(wsb + (size_t)32 * MB + 128 * 1024);
    float* hbuf          = (float*)(wsb + (size_t)33 * MB);
    float* ybuf          = (float*)(wsb + (size_t)34 * MB);   // 16 MiB -> ws34..50

    router_kernel<<<NTOK, 64, 0, stream>>>(znbuf, Wsw, bsw, routes);
    route_scan<<<1, 1024, 0, stream>>>(routes, slot_of_token, token_of_slot);
    ffn1<<<NE * CAP, 64, 0, stream>>>(znbuf, token_of_slot, W1, b1, hbuf);
    ffn2<<<NE * CAP, 256, 0, stream>>>(hbuf, token_of_slot, W2, b2, ybuf);

    assemble<<<NTOK, 256, 0, stream>>>(znbuf, ybuf, slot_of_token, (float*)d_out,
                                       (float*)d_out + (size_t)3 * NTOK * 1024);

    // passthrough outputs (overwrite dead attbuf/znbuf regions)
    hipMemcpyAsync(D + (size_t)32 * MB, (const void*)kx,
                   (size_t)NTOK * 1024 * 4, hipMemcpyDeviceToDevice, stream);
    hipMemcpyAsync(D + (size_t)64 * MB, (const void*)vx,
                   (size_t)NTOK * 1024 * 4, hipMemcpyDeviceToDevice, stream);
}